// Round 1
// baseline (736.861 us; speedup 1.0000x reference)
//
#include <hip/hip_runtime.h>
#include <hip/hip_bf16.h>

#define NROWS 4096
#define DIM   128
#define SCOLS 32768

typedef short bf16x8 __attribute__((ext_vector_type(8)));
typedef float f32x4  __attribute__((ext_vector_type(4)));

__device__ __forceinline__ unsigned short f2bf(float f) {
    // round-to-nearest-even fp32 -> bf16 (inputs are finite randn; no NaN path needed)
    unsigned int u = __builtin_bit_cast(unsigned int, f);
    u += 0x7fffu + ((u >> 16) & 1u);
    return (unsigned short)(u >> 16);
}

// 128x128 output tile per block, K=128 fully resident in LDS.
// LDS layout: row-major [128][128] bf16, 16B chunks XOR-swizzled by (row&15)
// -> 2-way bank aliasing on both ds_write and ds_read_b128 (free, m136).
__global__ __launch_bounds__(256, 2) void lsh_gemm(
    const float* __restrict__ x,
    const float* __restrict__ weight,
    const float* __restrict__ bias,
    const int*   __restrict__ ids,
    float*       __restrict__ out)
{
    __shared__ unsigned short lds_x[128 * 128];   // 32 KB
    __shared__ unsigned short lds_w[128 * 128];   // 32 KB  (total exactly 64 KB)

    const int t  = threadIdx.x;
    const int s0 = blockIdx.x * 128;   // sample (column) tile
    const int n0 = blockIdx.y * 128;   // x-row tile

    // ---- stage x tile: 128 rows x 32 float4, fp32 -> bf16 ----
    #pragma unroll
    for (int i = 0; i < 16; ++i) {
        int f   = t + i * 256;          // float4 index in tile
        int row = f >> 5;               // 32 float4 per row
        int c4  = f & 31;
        float4 v = ((const float4*)(x + (size_t)(n0 + row) * DIM))[c4];
        ushort4 b;
        b.x = f2bf(v.x); b.y = f2bf(v.y); b.z = f2bf(v.z); b.w = f2bf(v.w);
        int sw = (c4 >> 1) ^ (row & 15);                 // swizzled 16B chunk
        *(ushort4*)&lds_x[row * 128 + sw * 8 + (c4 & 1) * 4] = b;
    }
    // ---- stage gathered W tile: rows weight[ids[s0+j]], fp32 -> bf16 ----
    #pragma unroll
    for (int i = 0; i < 16; ++i) {
        int f   = t + i * 256;
        int row = f >> 5;
        int c4  = f & 31;
        int id  = ids[s0 + row];        // 32 lanes share one id -> one dword load
        float4 v = ((const float4*)(weight + (size_t)id * DIM))[c4];
        ushort4 b;
        b.x = f2bf(v.x); b.y = f2bf(v.y); b.z = f2bf(v.z); b.w = f2bf(v.w);
        int sw = (c4 >> 1) ^ (row & 15);
        *(ushort4*)&lds_w[row * 128 + sw * 8 + (c4 & 1) * 4] = b;
    }
    __syncthreads();

    const int lane = t & 63;
    const int wave = t >> 6;
    const int lrow = lane & 15;         // fragment row (A/B operand: row = lane&15)
    const int quad = lane >> 4;         // k = quad*8 + j
    const int wm   = (wave & 1) * 64;   // wave's 64-row sub-tile (n)
    const int wsc  = (wave >> 1) * 64;  // wave's 64-col sub-tile (s)

    f32x4 acc[4][4];
    #pragma unroll
    for (int a = 0; a < 4; ++a)
        #pragma unroll
        for (int b = 0; b < 4; ++b)
            acc[a][b] = (f32x4){0.f, 0.f, 0.f, 0.f};

    // K = 128 = 4 MFMA k-steps of 32
    #pragma unroll
    for (int kk = 0; kk < 4; ++kk) {
        bf16x8 af[4], bv[4];
        int cbase = kk * 4 + quad;       // 16B chunk index for this lane's k-slice
        #pragma unroll
        for (int i = 0; i < 4; ++i) {
            int rowa = wm  + i * 16 + lrow;   // rowa & 15 == lrow
            int rowb = wsc + i * 16 + lrow;
            af[i] = *(const bf16x8*)&lds_x[rowa * 128 + (cbase ^ lrow) * 8];
            bv[i] = *(const bf16x8*)&lds_w[rowb * 128 + (cbase ^ lrow) * 8];
        }
        #pragma unroll
        for (int tm = 0; tm < 4; ++tm)
            #pragma unroll
            for (int ts = 0; ts < 4; ++ts)
                acc[tm][ts] = __builtin_amdgcn_mfma_f32_16x16x32_bf16(
                    af[tm], bv[ts], acc[tm][ts], 0, 0, 0);
    }

    // ---- epilogue: + gathered bias, store fp32 ----
    // C/D layout: col = lane&15, row = quad*4 + reg   (m89/m91 verified)
    #pragma unroll
    for (int ts = 0; ts < 4; ++ts) {
        int colL = wsc + ts * 16 + lrow;
        int col  = s0 + colL;
        float bvps = bias[ids[s0 + colL]];   // L1-hot after staging
        #pragma unroll
        for (int tm = 0; tm < 4; ++tm) {
            int rowbase = n0 + wm + tm * 16 + quad * 4;
            #pragma unroll
            for (int r = 0; r < 4; ++r)
                out[(size_t)(rowbase + r) * SCOLS + col] = acc[tm][ts][r] + bvps;
        }
    }
}

// second output: sample_ids as float, appended after the logits
__global__ void ids_out_kernel(const int* __restrict__ ids, float* __restrict__ out)
{
    int i = blockIdx.x * 256 + threadIdx.x;
    if (i < SCOLS)
        out[(size_t)NROWS * SCOLS + i] = (float)ids[i];   // ids < 2^24 -> exact
}

extern "C" void kernel_launch(void* const* d_in, const int* in_sizes, int n_in,
                              void* d_out, int out_size, void* d_ws, size_t ws_size,
                              hipStream_t stream) {
    const float* x      = (const float*)d_in[0];
    const float* weight = (const float*)d_in[1];
    const float* bias   = (const float*)d_in[2];
    const int*   ids    = (const int*)d_in[3];
    float*       out    = (float*)d_out;

    hipLaunchKernelGGL(lsh_gemm, dim3(SCOLS / 128, NROWS / 128), dim3(256), 0, stream,
                       x, weight, bias, ids, out);
    hipLaunchKernelGGL(ids_out_kernel, dim3(SCOLS / 256), dim3(256), 0, stream,
                       ids, out);
}